// Round 7
// baseline (21.015 us; speedup 1.0000x reference)
//
#include <hip/hip_runtime.h>
#include <math.h>

#define NPTS 2048
#define NBATCH 8
#define NC (NBATCH * NPTS)
#define COUT 9
#define CELLS 1000      // 10x10x10 grid; width 1/9.99 = 0.1001 > radius + fp margin
#define CPB 8           // centers per block (4 waves x 2)
#define SCALE 65536.0f

// ONE dispatch. Each block rebuilds its batch's cell structure in LDS
// (histogram -> scan -> index scatter), then processes 8 centers with the
// 9-column stencil. Pair tests cut ~37x vs brute force; zero extra nodes.
__global__ __launch_bounds__(256) void pconv_local(
    const float* __restrict__ pts,    // [B,N,3]
    const float* __restrict__ attrs,  // [B,N,1]
    const float* __restrict__ cw,     // [COUT,1,16] flat
    const float* __restrict__ cb,     // [COUT]
    float* __restrict__ out)          // [B,N,COUT]
{
    const int t    = threadIdx.x;
    const int lane = t & 63;
    const int w    = t >> 6;
    const int blk  = blockIdx.x;              // 2048 blocks
    const int b    = blk >> 8;                // 256 blocks per batch
    const int cb0  = (blk & 255) * CPB;       // first center (index within batch)

    __shared__ int hist[CELLS];               // histogram -> ticket after scan
    __shared__ int starts[CELLS + 1];
    __shared__ int sidx[NPTS];                // cell-sorted point indices
    __shared__ int wt[4];
    __shared__ int s_sum[4][2][16];           // per-wave, per-center Q16 bins
    __shared__ int s_cnt[4][2][16];

    #pragma unroll
    for (int k = t; k < CELLS; k += 256) hist[k] = 0;
    __syncthreads();

    const float* pb = pts   + (size_t)b * NPTS * 3;
    const float* ab = attrs + (size_t)b * NPTS;

    // ---- histogram: 8 points per thread ----
    int cids[8];
    #pragma unroll
    for (int k = 0; k < 8; ++k) {
        const int j = t + k * 256;
        const float x = pb[j * 3 + 0], y = pb[j * 3 + 1], z = pb[j * 3 + 2];
        const int cid = ((int)(x * 9.99f) * 10 + (int)(y * 9.99f)) * 10
                      + (int)(z * 9.99f);
        cids[k] = cid;
        atomicAdd(&hist[cid], 1);
    }
    __syncthreads();

    // ---- exclusive scan over 1000 cells (4 per thread; validated R5) ----
    const int c0 = t * 4;
    int v0 = 0, v1 = 0, v2 = 0, v3 = 0;
    if (c0 < CELLS) { v0 = hist[c0]; v1 = hist[c0+1]; v2 = hist[c0+2]; v3 = hist[c0+3]; }
    const int s = v0 + v1 + v2 + v3;
    int sc = s;
    #pragma unroll
    for (int off = 1; off < 64; off <<= 1) {
        const int n = __shfl_up(sc, off);
        if (lane >= off) sc += n;
    }
    if (lane == 63) wt[w] = sc;
    __syncthreads();                  // also: all hist reads done -> safe to overwrite
    int wbase = 0;
    #pragma unroll
    for (int k = 0; k < 4; ++k) { const int x = wt[k]; if (k < w) wbase += x; }
    int excl = wbase + sc - s;
    if (c0 < CELLS) {
        starts[c0]     = excl; hist[c0]     = excl; excl += v0;
        starts[c0 + 1] = excl; hist[c0 + 1] = excl; excl += v1;
        starts[c0 + 2] = excl; hist[c0 + 2] = excl; excl += v2;
        starts[c0 + 3] = excl; hist[c0 + 3] = excl; excl += v3;
    }
    if (t == 0) starts[CELLS] = NPTS;
    __syncthreads();

    // ---- scatter indices (per-cell SETS deterministic; downstream integer
    //      accumulation commutative -> bit-stable output) ----
    #pragma unroll
    for (int k = 0; k < 8; ++k) {
        const int pos = atomicAdd(&hist[cids[k]], 1);
        sidx[pos] = t + k * 256;
    }
    __syncthreads();

    // ---- exact thresholds (validated R2-R6) ----
    //   sqrt_rn(d2) <= 0.1f    <=>  d2 <= T1
    //   trunc(dist/0.05f) >= 1 <=>  dist >= 0.05f  <=>  d2 >= T2
    constexpr double MIDR   = 26843547.0 / 268435456.0;
    constexpr double MIDR2  = MIDR * MIDR;
    constexpr double MID2   = 26843545.0 / 536870912.0;
    constexpr double MID2SQ = MID2 * MID2;
    float T1 = (float)MIDR2;  if ((double)T1 >= MIDR2)  T1 = nextafterf(T1, 0.0f);
    float T2 = (float)MID2SQ; if ((double)T2 <= MID2SQ) T2 = nextafterf(T2, 1.0f);

    float cwreg[16];
    float bias = 0.0f;
    if (lane < COUT) {
        bias = cb[lane];
        #pragma unroll
        for (int q = 0; q < 16; ++q) cwreg[q] = cw[lane * 16 + q];
    }

    // zero this wave's 32 bins (wave-private; LDS program order within wave)
    if (lane < 32) {
        s_sum[w][lane >> 4][lane & 15] = 0;
        s_cnt[w][lane >> 4][lane & 15] = 0;
    }

    // ---- main: 2 centers per wave via stencil enumeration ----
    #pragma unroll
    for (int cc = 0; cc < 2; ++cc) {
        const int ci = cb0 + w * 2 + cc;          // center index within batch
        const float cx = pb[ci * 3 + 0], cy = pb[ci * 3 + 1], cz = pb[ci * 3 + 2];
        const int gcell = ((int)(cx * 9.99f) * 10 + (int)(cy * 9.99f)) * 10
                        + (int)(cz * 9.99f);
        const int gx = gcell / 100, gy = (gcell / 10) % 10, gz = gcell % 10;

        // 9 stencil (x,y) columns; each a contiguous z-run in sorted order
        int rs = 0, len = 0;
        if (lane < 9) {
            const int nx = gx + lane / 3 - 1, ny = gy + lane % 3 - 1;
            if (nx >= 0 && nx < 10 && ny >= 0 && ny < 10) {
                const int zlo = gz > 0 ? gz - 1 : 0;
                const int zhi = gz < 9 ? gz + 1 : 9;
                const int base = (nx * 10 + ny) * 10;
                rs  = starts[base + zlo];
                len = starts[base + zhi + 1] - rs;
            }
        }
        int scn = len;
        #pragma unroll
        for (int off = 1; off < 16; off <<= 1) {
            const int n = __shfl_up(scn, off);
            if (lane >= off) scn += n;
        }
        const int T   = __shfl(scn, 8);
        const int pre = scn - len;
        int rs_a[9], pre_a[9];
        #pragma unroll
        for (int r = 0; r < 9; ++r) { rs_a[r] = __shfl(rs, r); pre_a[r] = __shfl(pre, r); }

        for (int idx0 = 0; idx0 < T; idx0 += 64) {   // T ~ 55: usually 1 iter
            const int idx = idx0 + lane;
            const bool act = idx < T;
            int r = 0;
            #pragma unroll
            for (int rr = 1; rr < 9; ++rr)
                if (idx >= pre_a[rr]) r = rr;        // last run with pre <= idx
            const int jj = act ? sidx[rs_a[r] + idx - pre_a[r]] : 0;
            const float px = pb[jj * 3 + 0];
            const float py = pb[jj * 3 + 1];
            const float pz = pb[jj * 3 + 2];
            const float aw = ab[jj];
            // strict IEEE, matches numpy (x*x + y*y) + z*z
            const float dx = __fsub_rn(cx, px);
            const float dy = __fsub_rn(cy, py);
            const float dz = __fsub_rn(cz, pz);
            const float d2 = __fadd_rn(__fadd_rn(__fmul_rn(dx, dx), __fmul_rn(dy, dy)),
                                       __fmul_rn(dz, dz));
            if (act && d2 <= T1) {
                const int oct = (dx >= 0.0f ? 1 : 0) + (dy >= 0.0f ? 2 : 0)
                              + (dz >= 0.0f ? 4 : 0);
                const int cell = (d2 >= T2 ? 8 : 0) + oct;
                const int av = __float2int_rn(aw * SCALE);
                atomicAdd(&s_sum[w][cc][cell], av);
                atomicAdd(&s_cnt[w][cc][cell], 1);
            }
        }

        // epilogue (wave-private bins; program order within wave)
        float mv = 0.0f;
        if (lane < 16) {
            const int ss = s_sum[w][cc][lane];
            const int nn = s_cnt[w][cc][lane];
            mv = ((float)ss * (1.0f / SCALE)) / (float)(nn ? nn : 1);
        }
        float acc = bias;
        #pragma unroll
        for (int q = 0; q < 16; ++q) acc = fmaf(__shfl(mv, q), cwreg[q], acc);
        if (lane < COUT)
            out[((size_t)b * NPTS + ci) * COUT + lane] = acc;
    }
}

extern "C" void kernel_launch(void* const* d_in, const int* in_sizes, int n_in,
                              void* d_out, int out_size, void* d_ws, size_t ws_size,
                              hipStream_t stream) {
    const float* pts   = (const float*)d_in[0];  // [8,2048,3]
    const float* attrs = (const float*)d_in[1];  // [8,2048,1]
    const float* cw    = (const float*)d_in[2];  // [9,1,16]
    const float* cb    = (const float*)d_in[3];  // [9]
    float* out = (float*)d_out;                  // [8,2048,9]

    pconv_local<<<NC / CPB, 256, 0, stream>>>(pts, attrs, cw, cb, out);
}

// Round 9
// 15.367 us; speedup vs baseline: 1.3675x; 1.3675x over previous
//
#include <hip/hip_runtime.h>
#include <math.h>

#define NPTS 2048
#define NBATCH 8
#define NC (NBATCH * NPTS)
#define COUT 9
#define CELLS 1000       // 10x10x10 grid; width 1/9.99 = 0.1001 > radius + fp margin
#define THREADS 512
#define CPB 32           // centers per block (8 waves x 4)
#define BPB (NPTS / CPB) // 64 blocks per batch
#define SCALE 65536.0f

// ONE dispatch. Each block rebuilds its batch's cell structure in LDS
// (histogram -> scan -> packed-float4 scatter), then its 8 waves process
// 4 centers each via the 9-column stencil.
// R9 fix vs R8: epilogue __shfl must run with ALL lanes active — ds_bpermute
// from an inactive source lane returns UNDEFINED data (ISA §6). Store-only
// is guarded now. Bin zeroing hoisted out of the center loop.
__global__ __launch_bounds__(THREADS) void pconv_local(
    const float* __restrict__ pts,    // [B,N,3]
    const float* __restrict__ attrs,  // [B,N,1]
    const float* __restrict__ cw,     // [COUT,1,16] flat
    const float* __restrict__ cbias,  // [COUT]
    float* __restrict__ out)          // [B,N,COUT]
{
    const int t    = threadIdx.x;
    const int lane = t & 63;
    const int w    = t >> 6;                  // 8 waves
    const int blk  = blockIdx.x;              // 512 blocks
    const int b    = blk / BPB;
    const int cb0  = (blk % BPB) * CPB;       // first center (index within batch)

    __shared__ int    hist[CELLS];            // histogram -> ticket after scan
    __shared__ int    starts[CELLS + 1];
    __shared__ float4 spts[NPTS];             // cell-sorted packed {x,y,z,attr}
    __shared__ int    wt[8];
    __shared__ int    s_sum[8][4][16];        // per-wave, per-center Q16 bins
    __shared__ int    s_cnt[8][4][16];

    for (int k = t; k < CELLS; k += THREADS) hist[k] = 0;
    __syncthreads();

    const float* pb = pts   + (size_t)b * NPTS * 3;
    const float* ab = attrs + (size_t)b * NPTS;

    // ---- histogram: 4 points per thread (coalesced) ----
    float4 p4[4]; int cids[4];
    #pragma unroll
    for (int k = 0; k < 4; ++k) {
        const int j = t + k * THREADS;
        const float x = pb[j * 3 + 0], y = pb[j * 3 + 1], z = pb[j * 3 + 2];
        p4[k] = make_float4(x, y, z, ab[j]);
        cids[k] = ((int)(x * 9.99f) * 10 + (int)(y * 9.99f)) * 10 + (int)(z * 9.99f);
        atomicAdd(&hist[cids[k]], 1);
    }
    __syncthreads();

    // ---- exclusive scan over 1000 cells (2 per thread) ----
    const int c0 = t * 2;
    int v0 = 0, v1 = 0;
    if (c0 < CELLS) { v0 = hist[c0]; v1 = hist[c0 + 1]; }
    const int s = v0 + v1;
    int sc = s;
    #pragma unroll
    for (int off = 1; off < 64; off <<= 1) {
        const int n = __shfl_up(sc, off);
        if (lane >= off) sc += n;
    }
    if (lane == 63) wt[w] = sc;
    __syncthreads();                 // also orders hist reads before overwrite
    int wbase = 0;
    #pragma unroll
    for (int k = 0; k < 8; ++k) { const int x = wt[k]; if (k < w) wbase += x; }
    int excl = wbase + sc - s;
    if (c0 < CELLS) {
        starts[c0]     = excl; hist[c0]     = excl; excl += v0;
        starts[c0 + 1] = excl; hist[c0 + 1] = excl;
    }
    if (t == 0) starts[CELLS] = NPTS;
    __syncthreads();

    // ---- scatter packed points (per-cell SETS deterministic; downstream
    //      integer accumulation commutative -> bit-stable output) ----
    #pragma unroll
    for (int k = 0; k < 4; ++k) {
        const int pos = atomicAdd(&hist[cids[k]], 1);
        spts[pos] = p4[k];
    }
    __syncthreads();

    // ---- exact thresholds (validated R2-R7) ----
    //   sqrt_rn(d2) <= 0.1f    <=>  d2 <= T1
    //   trunc(dist/0.05f) >= 1 <=>  dist >= 0.05f  <=>  d2 >= T2
    constexpr double MIDR   = 26843547.0 / 268435456.0;
    constexpr double MIDR2  = MIDR * MIDR;
    constexpr double MID2   = 26843545.0 / 536870912.0;
    constexpr double MID2SQ = MID2 * MID2;
    float T1 = (float)MIDR2;  if ((double)T1 >= MIDR2)  T1 = nextafterf(T1, 0.0f);
    float T2 = (float)MID2SQ; if ((double)T2 <= MID2SQ) T2 = nextafterf(T2, 1.0f);

    // epilogue weights: EVERY lane loads a valid row (o = lane % 9) so the
    // converged epilogue below never touches uninitialized registers
    const int o_ep = lane % 9;
    float bias = cbias[o_ep];
    float cwreg[16];
    #pragma unroll
    for (int q = 0; q < 16; ++q) cwreg[q] = cw[o_ep * 16 + q];

    // zero this wave's 64 bins (4 centers x 16 cells) once, all lanes
    s_sum[w][lane >> 4][lane & 15] = 0;
    s_cnt[w][lane >> 4][lane & 15] = 0;

    // ---- main: 4 centers per wave via stencil enumeration ----
    #pragma unroll
    for (int cc = 0; cc < 4; ++cc) {
        const int ci = cb0 + w * 4 + cc;          // center index within batch
        const float cx = pb[ci * 3 + 0], cy = pb[ci * 3 + 1], cz = pb[ci * 3 + 2];
        const int gx = (int)(cx * 9.99f), gy = (int)(cy * 9.99f), gz = (int)(cz * 9.99f);

        // 9 stencil (x,y) columns; each a contiguous z-run in sorted order
        int rs = 0, len = 0;
        if (lane < 9) {
            const int nx = gx + lane / 3 - 1, ny = gy + lane % 3 - 1;
            if (nx >= 0 && nx < 10 && ny >= 0 && ny < 10) {
                const int zlo = gz > 0 ? gz - 1 : 0;
                const int zhi = gz < 9 ? gz + 1 : 9;
                const int base = (nx * 10 + ny) * 10;
                rs  = starts[base + zlo];
                len = starts[base + zhi + 1] - rs;
            }
        }
        int scn = len;                            // shfl scan: all lanes converged
        #pragma unroll
        for (int off = 1; off < 16; off <<= 1) {
            const int n = __shfl_up(scn, off);
            if (lane >= off) scn += n;
        }
        const int T   = __shfl(scn, 8);
        const int pre = scn - len;
        int rs_a[9], pre_a[9];
        #pragma unroll
        for (int r = 0; r < 9; ++r) { rs_a[r] = __shfl(rs, r); pre_a[r] = __shfl(pre, r); }

        for (int idx0 = 0; idx0 < T; idx0 += 64) {   // T ~ 55: usually 1 iter
            const int idx = idx0 + lane;
            const bool act = idx < T;
            int r = 0;
            #pragma unroll
            for (int rr = 1; rr < 9; ++rr)
                if (idx >= pre_a[rr]) r = rr;        // last run with pre <= idx
            const int cand = act ? (rs_a[r] + idx - pre_a[r]) : 0;
            const float4 pj = spts[cand];            // one ds_read_b128
            // strict IEEE, matches numpy (x*x + y*y) + z*z
            const float dx = __fsub_rn(cx, pj.x);
            const float dy = __fsub_rn(cy, pj.y);
            const float dz = __fsub_rn(cz, pj.z);
            const float d2 = __fadd_rn(__fadd_rn(__fmul_rn(dx, dx), __fmul_rn(dy, dy)),
                                       __fmul_rn(dz, dz));
            if (act && d2 <= T1) {
                const int oct = (dx >= 0.0f ? 1 : 0) + (dy >= 0.0f ? 2 : 0)
                              + (dz >= 0.0f ? 4 : 0);
                const int cell = (d2 >= T2 ? 8 : 0) + oct;
                const int av = __float2int_rn(pj.w * SCALE);
                atomicAdd(&s_sum[w][cc][cell], av);
                atomicAdd(&s_cnt[w][cc][cell], 1);
            }
        }
    }

    // ---- batched epilogue, FULLY CONVERGED (all 64 lanes run every shfl) ----
    const int ecc = lane >> 4, eq = lane & 15;
    const int ss = s_sum[w][ecc][eq];
    const int nn = s_cnt[w][ecc][eq];
    const float mv = ((float)ss * (1.0f / SCALE)) / (float)(nn ? nn : 1);

    const int occ  = lane / 9;                    // 0..7; only 0..3 stored
    const int osel = occ < 4 ? occ : 0;           // clamp shfl index for lanes 36+
    float acc = bias;
    #pragma unroll
    for (int q = 0; q < 16; ++q)
        acc = fmaf(__shfl(mv, osel * 16 + q), cwreg[q], acc);

    if (lane < 36)
        out[((size_t)b * NPTS + cb0 + w * 4 + occ) * COUT + o_ep] = acc;
}

extern "C" void kernel_launch(void* const* d_in, const int* in_sizes, int n_in,
                              void* d_out, int out_size, void* d_ws, size_t ws_size,
                              hipStream_t stream) {
    const float* pts   = (const float*)d_in[0];  // [8,2048,3]
    const float* attrs = (const float*)d_in[1];  // [8,2048,1]
    const float* cw    = (const float*)d_in[2];  // [9,1,16]
    const float* cb    = (const float*)d_in[3];  // [9]
    float* out = (float*)d_out;                  // [8,2048,9]

    pconv_local<<<NC / CPB, THREADS, 0, stream>>>(pts, attrs, cw, cb, out);
}

// Round 10
// 15.220 us; speedup vs baseline: 1.3807x; 1.0097x over previous
//
#include <hip/hip_runtime.h>
#include <math.h>

#define NPTS 2048
#define NBATCH 8
#define NC (NBATCH * NPTS)
#define COUT 9
#define CELLS 1000       // 10x10x10 grid; width 1/9.99 = 0.1001 > radius + fp margin
#define THREADS 1024
#define NWAVES (THREADS / 64)
#define CPB 64           // centers per block (16 waves x 4)
#define BPB (NPTS / CPB) // 32 blocks per batch
#define SCALE 65536.0f

// ONE dispatch, 256 blocks (1/CU). Each block rebuilds its batch's cell
// structure in LDS (histogram -> scan -> packed-float4 scatter), then its
// 16 waves process 4 centers each via the 9-column stencil. Build work
// halved vs R9 (CPB 32->64); main loop identical.
__global__ __launch_bounds__(THREADS) void pconv_local(
    const float* __restrict__ pts,    // [B,N,3]
    const float* __restrict__ attrs,  // [B,N,1]
    const float* __restrict__ cw,     // [COUT,1,16] flat
    const float* __restrict__ cbias,  // [COUT]
    float* __restrict__ out)          // [B,N,COUT]
{
    const int t    = threadIdx.x;
    const int lane = t & 63;
    const int w    = t >> 6;                  // 16 waves
    const int blk  = blockIdx.x;              // 256 blocks
    const int b    = blk / BPB;
    const int cb0  = (blk % BPB) * CPB;       // first center (index within batch)

    __shared__ int    hist[CELLS];            // histogram -> ticket after scan
    __shared__ int    starts[CELLS + 1];
    __shared__ float4 spts[NPTS];             // cell-sorted packed {x,y,z,attr}
    __shared__ int    wt[NWAVES];
    __shared__ int    s_sum[NWAVES][4][16];   // per-wave, per-center Q16 bins
    __shared__ int    s_cnt[NWAVES][4][16];

    if (t < CELLS) hist[t] = 0;
    __syncthreads();

    const float* pb = pts   + (size_t)b * NPTS * 3;
    const float* ab = attrs + (size_t)b * NPTS;

    // ---- histogram: 2 points per thread ----
    float4 p4[2]; int cids[2];
    #pragma unroll
    for (int k = 0; k < 2; ++k) {
        const int j = t + k * THREADS;
        const float x = pb[j * 3 + 0], y = pb[j * 3 + 1], z = pb[j * 3 + 2];
        p4[k] = make_float4(x, y, z, ab[j]);
        cids[k] = ((int)(x * 9.99f) * 10 + (int)(y * 9.99f)) * 10 + (int)(z * 9.99f);
        atomicAdd(&hist[cids[k]], 1);
    }
    __syncthreads();

    // ---- exclusive scan over 1000 cells (1 per thread) ----
    const int v = (t < CELLS) ? hist[t] : 0;
    int sc = v;
    #pragma unroll
    for (int off = 1; off < 64; off <<= 1) {
        const int n = __shfl_up(sc, off);
        if (lane >= off) sc += n;
    }
    if (lane == 63) wt[w] = sc;
    __syncthreads();                 // also orders hist reads before overwrite
    int wbase = 0;
    #pragma unroll
    for (int k = 0; k < NWAVES; ++k) { const int x = wt[k]; if (k < w) wbase += x; }
    const int excl = wbase + sc - v;
    if (t < CELLS) {
        starts[t] = excl;
        hist[t]   = excl;            // reuse as scatter ticket
    }
    if (t == 0) starts[CELLS] = NPTS;
    __syncthreads();

    // ---- scatter packed points (per-cell SETS deterministic; downstream
    //      integer accumulation commutative -> bit-stable output) ----
    #pragma unroll
    for (int k = 0; k < 2; ++k) {
        const int pos = atomicAdd(&hist[cids[k]], 1);
        spts[pos] = p4[k];
    }
    __syncthreads();

    // ---- exact thresholds (validated R2-R9) ----
    //   sqrt_rn(d2) <= 0.1f    <=>  d2 <= T1
    //   trunc(dist/0.05f) >= 1 <=>  dist >= 0.05f  <=>  d2 >= T2
    constexpr double MIDR   = 26843547.0 / 268435456.0;
    constexpr double MIDR2  = MIDR * MIDR;
    constexpr double MID2   = 26843545.0 / 536870912.0;
    constexpr double MID2SQ = MID2 * MID2;
    float T1 = (float)MIDR2;  if ((double)T1 >= MIDR2)  T1 = nextafterf(T1, 0.0f);
    float T2 = (float)MID2SQ; if ((double)T2 <= MID2SQ) T2 = nextafterf(T2, 1.0f);

    // epilogue weights: EVERY lane loads a valid row (converged epilogue)
    const int o_ep = lane % 9;
    float bias = cbias[o_ep];
    float cwreg[16];
    #pragma unroll
    for (int q = 0; q < 16; ++q) cwreg[q] = cw[o_ep * 16 + q];

    // zero this wave's 64 bins (4 centers x 16 cells) once, all lanes
    s_sum[w][lane >> 4][lane & 15] = 0;
    s_cnt[w][lane >> 4][lane & 15] = 0;

    // ---- main: 4 centers per wave via stencil enumeration ----
    #pragma unroll
    for (int cc = 0; cc < 4; ++cc) {
        const int ci = cb0 + w * 4 + cc;          // center index within batch
        const float cx = pb[ci * 3 + 0], cy = pb[ci * 3 + 1], cz = pb[ci * 3 + 2];
        const int gx = (int)(cx * 9.99f), gy = (int)(cy * 9.99f), gz = (int)(cz * 9.99f);

        // 9 stencil (x,y) columns; each a contiguous z-run in sorted order
        int rs = 0, len = 0;
        if (lane < 9) {
            const int nx = gx + lane / 3 - 1, ny = gy + lane % 3 - 1;
            if (nx >= 0 && nx < 10 && ny >= 0 && ny < 10) {
                const int zlo = gz > 0 ? gz - 1 : 0;
                const int zhi = gz < 9 ? gz + 1 : 9;
                const int base = (nx * 10 + ny) * 10;
                rs  = starts[base + zlo];
                len = starts[base + zhi + 1] - rs;
            }
        }
        int scn = len;                            // shfl scan: all lanes converged
        #pragma unroll
        for (int off = 1; off < 16; off <<= 1) {
            const int n = __shfl_up(scn, off);
            if (lane >= off) scn += n;
        }
        const int T   = __shfl(scn, 8);
        const int pre = scn - len;
        int rs_a[9], pre_a[9];
        #pragma unroll
        for (int r = 0; r < 9; ++r) { rs_a[r] = __shfl(rs, r); pre_a[r] = __shfl(pre, r); }

        for (int idx0 = 0; idx0 < T; idx0 += 64) {   // T ~ 55: usually 1 iter
            const int idx = idx0 + lane;
            const bool act = idx < T;
            int r = 0;
            #pragma unroll
            for (int rr = 1; rr < 9; ++rr)
                if (idx >= pre_a[rr]) r = rr;        // last run with pre <= idx
            const int cand = act ? (rs_a[r] + idx - pre_a[r]) : 0;
            const float4 pj = spts[cand];            // one ds_read_b128
            // strict IEEE, matches numpy (x*x + y*y) + z*z
            const float dx = __fsub_rn(cx, pj.x);
            const float dy = __fsub_rn(cy, pj.y);
            const float dz = __fsub_rn(cz, pj.z);
            const float d2 = __fadd_rn(__fadd_rn(__fmul_rn(dx, dx), __fmul_rn(dy, dy)),
                                       __fmul_rn(dz, dz));
            if (act && d2 <= T1) {
                const int oct = (dx >= 0.0f ? 1 : 0) + (dy >= 0.0f ? 2 : 0)
                              + (dz >= 0.0f ? 4 : 0);
                const int cell = (d2 >= T2 ? 8 : 0) + oct;
                const int av = __float2int_rn(pj.w * SCALE);
                atomicAdd(&s_sum[w][cc][cell], av);
                atomicAdd(&s_cnt[w][cc][cell], 1);
            }
        }
    }

    // ---- batched epilogue, FULLY CONVERGED (all 64 lanes run every shfl) ----
    const int ecc = lane >> 4, eq = lane & 15;
    const int ss = s_sum[w][ecc][eq];
    const int nn = s_cnt[w][ecc][eq];
    const float mv = ((float)ss * (1.0f / SCALE)) / (float)(nn ? nn : 1);

    const int occ  = lane / 9;                    // 0..7; only 0..3 stored
    const int osel = occ < 4 ? occ : 0;           // clamp shfl index for lanes 36+
    float acc = bias;
    #pragma unroll
    for (int q = 0; q < 16; ++q)
        acc = fmaf(__shfl(mv, osel * 16 + q), cwreg[q], acc);

    if (lane < 36)
        out[((size_t)b * NPTS + cb0 + w * 4 + occ) * COUT + o_ep] = acc;
}

extern "C" void kernel_launch(void* const* d_in, const int* in_sizes, int n_in,
                              void* d_out, int out_size, void* d_ws, size_t ws_size,
                              hipStream_t stream) {
    const float* pts   = (const float*)d_in[0];  // [8,2048,3]
    const float* attrs = (const float*)d_in[1];  // [8,2048,1]
    const float* cw    = (const float*)d_in[2];  // [9,1,16]
    const float* cb    = (const float*)d_in[3];  // [9]
    float* out = (float*)d_out;                  // [8,2048,9]

    pconv_local<<<NC / CPB, THREADS, 0, stream>>>(pts, attrs, cw, cb, out);
}